// Round 9
// baseline (675.382 us; speedup 1.0000x reference)
//
#include <hip/hip_runtime.h>
#include <stdint.h>

#define BN_EPS 1e-5f
#define TPB 8   // tiles per block in msg pipeline

typedef __bf16 bf16x8 __attribute__((ext_vector_type(8)));
typedef __bf16 bf16x2 __attribute__((ext_vector_type(2)));
typedef float  f32x4  __attribute__((ext_vector_type(4)));
typedef float  f32x2  __attribute__((ext_vector_type(2)));

__device__ __forceinline__ unsigned short f2bf(float f) {
    unsigned u = __float_as_uint(f);
    unsigned r = (u + 0x7FFFu + ((u >> 16) & 1u)) >> 16;
    return (unsigned short)r;
}
// HW packed f32x2 -> bf16x2 (v_cvt_pk_bf16_f32), RNE
__device__ __forceinline__ unsigned pkb(float a, float b) {
    f32x2 f; f.x = a; f.y = b;
    bf16x2 h = __builtin_convertvector(f, bf16x2);
    return *(unsigned*)&h;
}
// packed relu(p + q) on bf16 pairs
__device__ __forceinline__ unsigned ar2(unsigned p, unsigned q) {
    f32x2 a, b;
    a.x = __uint_as_float(p << 16);
    a.y = __uint_as_float(p & 0xFFFF0000u);
    b.x = __uint_as_float(q << 16);
    b.y = __uint_as_float(q & 0xFFFF0000u);
    f32x2 s = a + b;
    return pkb(fmaxf(s.x, 0.f), fmaxf(s.y, 0.f));
}
// LDS swizzle, 256-col ushort tile: 16B blocks XOR'd by row&7
__device__ __forceinline__ int swz(int row, int k) {
    const int blk = k >> 3;
    const int sb = (blk & 24) | ((blk ^ row) & 7);
    return (row << 8) + (sb << 3) + (k & 7);
}
// LDS swizzle, 128-col ushort tile
__device__ __forceinline__ int swz128(int row, int k) {
    const int blk = k >> 3;
    const int sb = (blk & 8) | ((blk ^ row) & 7);
    return (row << 7) + (sb << 3) + (k & 7);
}

// prep: W folds, sign masks, BN consts (t1/t2), target histogram
__global__ void prep_kernel(
    const int* __restrict__ eidx,
    int E, int M,
    const float* __restrict__ W1, const float* __restrict__ W2, const float* __restrict__ W3,
    const float* __restrict__ b1, const float* __restrict__ g1, const float* __restrict__ be1,
    const float* __restrict__ m1, const float* __restrict__ v1,
    const float* __restrict__ b2, const float* __restrict__ g2, const float* __restrict__ be2,
    const float* __restrict__ m2, const float* __restrict__ v2,
    const float* __restrict__ b3, const float* __restrict__ g3, const float* __restrict__ be3,
    const float* __restrict__ m3, const float* __restrict__ v3,
    unsigned short* __restrict__ W1b, unsigned short* __restrict__ W2b,
    unsigned short* __restrict__ W3b, float* __restrict__ consts,
    unsigned* __restrict__ mask2, unsigned* __restrict__ count)
{
    const int idx = blockIdx.x * 256 + threadIdx.x;
    if (idx < 65536) {
        const int row = idx >> 8, c = idx & 255;
        float w1v = (c < 128) ? (W1[row * 256 + c] - W1[row * 256 + c + 128])
                              : W1[row * 256 + c];
        W1b[idx] = f2bf(w1v);
        const float s1c = g1[c] * rsqrtf(v1[c] + BN_EPS);
        W2b[idx] = f2bf(W2[idx] * s1c);
        const float s2c = g2[c] * rsqrtf(v2[c] + BN_EPS);
        W3b[idx] = f2bf(W3[idx] * s2c);
    }
    if (idx < 128) {
        const float sa = g2[2 * idx]     * rsqrtf(v2[2 * idx]     + BN_EPS);
        const float sb = g2[2 * idx + 1] * rsqrtf(v2[2 * idx + 1] + BN_EPS);
        mask2[idx] = (sa < 0.f ? 0xFFFFu : 0u) | ((sb < 0.f ? 0xFFFFu : 0u) << 16);
    }
    if (idx < 768) {
        const int l = idx >> 8, c = idx & 255;
        const float* bp  = l == 0 ? b1  : (l == 1 ? b2  : b3);
        const float* gp  = l == 0 ? g1  : (l == 1 ? g2  : g3);
        const float* bep = l == 0 ? be1 : (l == 1 ? be2 : be3);
        const float* mp  = l == 0 ? m1  : (l == 1 ? m2  : m3);
        const float* vp  = l == 0 ? v1  : (l == 1 ? v2  : v3);
        const float s = gp[c] * rsqrtf(vp[c] + BN_EPS);
        consts[l * 768 + c]       = bp[c];          // matvec_kernel adds folds
        consts[l * 768 + 256 + c] = s;
        consts[l * 768 + 512 + c] = bep[c] - mp[c] * s;
    }
    if (idx < M) {
        const int tgt = (idx < E) ? eidx[E + idx] : (idx - E);
        atomicAdd(&count[tgt], 1u);
    }
}

// matvec: b2'' += W2 @ t1, b3' += W3 @ t2 (one wave per output col; shfl reduce)
__global__ __launch_bounds__(256) void matvec_kernel(
    const float* __restrict__ W2, const float* __restrict__ W3,
    float* __restrict__ consts)
{
    const int g = blockIdx.x * 4 + (threadIdx.x >> 6);   // 0..511
    const int lane = threadIdx.x & 63;
    const int l = g >> 8, c = g & 255;
    const float* W = l ? W3 : W2;
    const float* tv = consts + (l ? (768 + 512) : 512);
    float4 w4 = *(const float4*)&W[c * 256 + lane * 4];
    float4 t4 = *(const float4*)&tv[lane * 4];
    float s = w4.x * t4.x + w4.y * t4.y + w4.z * t4.z + w4.w * t4.w;
    #pragma unroll
    for (int d = 1; d < 64; d <<= 1) s += __shfl_xor(s, d);
    if (lane == 0) consts[(l ? 1536 : 768) + c] += s;
}

// pq: P' = X@(W1a-W1b)^T + b1, Q = X@W1b^T (reads fp32 x directly)
__global__ __launch_bounds__(512) void pq_kernel(
    const float* __restrict__ x, int N,
    const unsigned short* __restrict__ W1b,
    const float* __restrict__ consts,
    unsigned short* __restrict__ Pb, unsigned short* __restrict__ Qb)
{
    __shared__ unsigned short Xs[64 * 128];

    const int t = threadIdx.x;
    const int base = blockIdx.x * 64;

    {
        const int row = t >> 3, part = t & 7;
        const int node = base + row;
        const int c0 = part * 16;
        if (node < N) {
            const float* s = x + (size_t)node * 128 + c0;
            float4 a0 = *(const float4*)(s);
            float4 a1 = *(const float4*)(s + 4);
            float4 a2 = *(const float4*)(s + 8);
            float4 a3 = *(const float4*)(s + 12);
            uint4 p0 = {pkb(a0.x, a0.y), pkb(a0.z, a0.w), pkb(a1.x, a1.y), pkb(a1.z, a1.w)};
            uint4 p1 = {pkb(a2.x, a2.y), pkb(a2.z, a2.w), pkb(a3.x, a3.y), pkb(a3.z, a3.w)};
            *(uint4*)&Xs[swz128(row, c0)]     = p0;
            *(uint4*)&Xs[swz128(row, c0 + 8)] = p1;
        } else {
            const uint4 z = {0u, 0u, 0u, 0u};
            *(uint4*)&Xs[swz128(row, c0)]     = z;
            *(uint4*)&Xs[swz128(row, c0 + 8)] = z;
        }
    }
    __syncthreads();

    const int lane = t & 63;
    const int wv   = t >> 6;
    const int n16  = lane & 15;
    const int qd   = lane >> 4;
    const int wc   = wv * 32;

    const f32x4 vzero = {0.f, 0.f, 0.f, 0.f};

    #pragma unroll
    for (int ph = 0; ph < 2; ph++) {
        f32x4 acc[2][4];
        #pragma unroll
        for (int i = 0; i < 2; i++)
            #pragma unroll
            for (int j = 0; j < 4; j++) acc[i][j] = vzero;

        #pragma unroll
        for (int ks = 0; ks < 4; ks++) {
            const int k0 = ks * 32 + qd * 8;
            bf16x8 a[2], b[4];
            #pragma unroll
            for (int ci = 0; ci < 2; ci++)
                a[ci] = *(const bf16x8*)&W1b[(size_t)(wc + ci * 16 + n16) * 256 + ph * 128 + k0];
            #pragma unroll
            for (int rj = 0; rj < 4; rj++)
                b[rj] = *(const bf16x8*)&Xs[swz128(rj * 16 + n16, k0)];
            #pragma unroll
            for (int ci = 0; ci < 2; ci++)
                #pragma unroll
                for (int rj = 0; rj < 4; rj++)
                    acc[ci][rj] = __builtin_amdgcn_mfma_f32_16x16x32_bf16(a[ci], b[rj], acc[ci][rj], 0, 0, 0);
        }

        unsigned short* dst = ph == 0 ? Pb : Qb;
        #pragma unroll
        for (int ci = 0; ci < 2; ci++) {
            const int col0 = wc + ci * 16 + qd * 4;
            float4 bb = {0.f, 0.f, 0.f, 0.f};
            if (ph == 0) bb = *(const float4*)&consts[col0];
            #pragma unroll
            for (int rj = 0; rj < 4; rj++) {
                const int node = base + rj * 16 + n16;
                if (node < N) {
                    uint2 p = {pkb(acc[ci][rj][0] + bb.x, acc[ci][rj][1] + bb.y),
                               pkb(acc[ci][rj][2] + bb.z, acc[ci][rj][3] + bb.w)};
                    *(uint2*)(dst + (size_t)node * 256 + col0) = p;
                }
            }
        }
    }
}

__global__ __launch_bounds__(1024) void scan_kernel(
    const unsigned* __restrict__ count, unsigned* __restrict__ cursor, int N)
{
    __shared__ unsigned part[1024];
    const int t = threadIdx.x;
    const int per = (N + 1023) / 1024;
    const int b = t * per;
    unsigned s = 0;
    if (b + per <= N && (per & 3) == 0) {
        for (int i = 0; i < per; i += 4) {
            uint4 c4 = *(const uint4*)(count + b + i);
            s += c4.x + c4.y + c4.z + c4.w;
        }
    } else {
        for (int i = 0; i < per; i++) if (b + i < N) s += count[b + i];
    }
    part[t] = s;
    __syncthreads();
    for (int off = 1; off < 1024; off <<= 1) {
        unsigned v = (t >= off) ? part[t - off] : 0u;
        __syncthreads();
        part[t] += v;
        __syncthreads();
    }
    unsigned run = (t > 0) ? part[t - 1] : 0u;
    for (int i = 0; i < per; i++) {
        if (b + i < N) {
            unsigned c = count[b + i];
            cursor[b + i] = run;
            run += c;
        }
    }
}

__global__ void scatter_kernel(const int* __restrict__ eidx, int E, int M,
                               unsigned* __restrict__ cursor, int* __restrict__ spair)
{
    const int i = blockIdx.x * 256 + threadIdx.x;
    if (i < M) {
        int s, tg;
        if (i < E) { s = eidx[i]; tg = eidx[E + i]; }
        else       { s = tg = i - E; }
        const unsigned pos = atomicAdd(&cursor[tg], 1u);
        int2* p = (int2*)spair;
        p[pos] = make_int2(s, tg);
    }
}

// Persistent 8-tile pipeline: dbuf LDS; next tile's P/Q loads issued before
// GEMM2 so gather latency hides under MFMA. Segmax = R7 LDS form.
__global__ __launch_bounds__(512, 4) void msg_kernel(
    const unsigned short* __restrict__ Pb,
    const unsigned short* __restrict__ Qb,
    const int* __restrict__ spair,   // [M] (src,tgt) pairs, sorted by tgt
    int M,
    const unsigned short* __restrict__ W2b,
    const float* __restrict__ consts,
    const unsigned* __restrict__ mask2,
    unsigned* __restrict__ agg)
{
    __shared__ unsigned short At[2][64 * 256];   // 64 KiB

    const int t = threadIdx.x;
    const int row = t >> 3, part = t & 7;
    const int c0 = part * 32;
    const int lane = t & 63;
    const int wv   = t >> 6;
    const int n16  = lane & 15;
    const int qd   = lane >> 4;
    const int wc   = wv * 32;
    const int tile0 = blockIdx.x * TPB;

    uint4 P4[4], Q4[4];

    // load tile k's P/Q rows for this thread into regs
    auto loadTile = [&](int k) {
        const int slot = (tile0 + k) * 64 + row;
        if (slot < M) {
            const int2 pr = *(const int2*)(spair + 2 * slot);
            const unsigned short* Pp = Pb + (size_t)pr.y * 256 + c0;
            const unsigned short* Qp = Qb + (size_t)pr.x * 256 + c0;
            #pragma unroll
            for (int w = 0; w < 4; w++) P4[w] = *(const uint4*)(Pp + w * 8);
            #pragma unroll
            for (int w = 0; w < 4; w++) Q4[w] = *(const uint4*)(Qp + w * 8);
        } else {
            const uint4 z = {0u, 0u, 0u, 0u};
            #pragma unroll
            for (int w = 0; w < 4; w++) { P4[w] = z; Q4[w] = z; }
        }
    };
    // u1 = relu(P+Q) -> LDS buf (zeros for invalid rows since P=Q=0)
    auto writeU1 = [&](int buf) {
        #pragma unroll
        for (int w = 0; w < 4; w++) {
            uint4 u;
            u.x = ar2(P4[w].x, Q4[w].x);
            u.y = ar2(P4[w].y, Q4[w].y);
            u.z = ar2(P4[w].z, Q4[w].z);
            u.w = ar2(P4[w].w, Q4[w].w);
            *(uint4*)&At[buf][swz(row, c0 + w * 8)] = u;
        }
    };

    loadTile(0);
    writeU1(0);
    __syncthreads();

    const f32x4 vzero = {0.f, 0.f, 0.f, 0.f};
    const float* B2 = consts + 768;

    for (int i = 0; i < TPB; i++) {
        const int u = i & 1, v = u ^ 1;

        // issue next tile's global loads (consumed after GEMM2)
        if (i + 1 < TPB) loadTile(i + 1);

        f32x4 acc[2][4];
        #pragma unroll
        for (int a = 0; a < 2; a++)
            #pragma unroll
            for (int j = 0; j < 4; j++) acc[a][j] = vzero;

        // ---- GEMM2 from At[u] ----
        #pragma unroll
        for (int ks = 0; ks < 8; ks++) {
            const int k0 = ks * 32 + qd * 8;
            bf16x8 a[2], b[4];
            #pragma unroll
            for (int ci = 0; ci < 2; ci++)
                a[ci] = *(const bf16x8*)&W2b[(size_t)(wc + ci * 16 + n16) * 256 + k0];
            #pragma unroll
            for (int rj = 0; rj < 4; rj++)
                b[rj] = *(const bf16x8*)&At[u][swz(rj * 16 + n16, k0)];
            #pragma unroll
            for (int ci = 0; ci < 2; ci++)
                #pragma unroll
                for (int rj = 0; rj < 4; rj++)
                    acc[ci][rj] = __builtin_amdgcn_mfma_f32_16x16x32_bf16(a[ci], b[rj], acc[ci][rj], 0, 0, 0);
        }
        __syncthreads();   // all waves done reading At[u]; At[v] writable

        // ---- epi2 keys -> At[u] ----
        #pragma unroll
        for (int ci = 0; ci < 2; ci++) {
            const int col0 = wc + ci * 16 + qd * 4;
            const float4 bb = *(const float4*)&B2[col0];
            const uint2 mk = *(const uint2*)&mask2[col0 >> 1];
            #pragma unroll
            for (int rj = 0; rj < 4; rj++) {
                const int rr = rj * 16 + n16;
                float r0 = fmaxf(acc[ci][rj][0] + bb.x, 0.f);
                float r1 = fmaxf(acc[ci][rj][1] + bb.y, 0.f);
                float r2 = fmaxf(acc[ci][rj][2] + bb.z, 0.f);
                float r3 = fmaxf(acc[ci][rj][3] + bb.w, 0.f);
                uint2 p = {pkb(r0, r1) ^ mk.x, pkb(r2, r3) ^ mk.y};
                *(uint2*)&At[u][swz(rr, col0)] = p;
            }
        }
        // ---- gather-write next u1 -> At[v] (stalls on its vmcnt here) ----
        if (i + 1 < TPB) writeU1(v);
        __syncthreads();

        // ---- segmented max over At[u]: wave = 16 rows x 128 cols ----
        {
            const int r0i = (wv & 3) * 16;
            const int cb = (wv >> 2) * 128 + lane * 2;
            const int slot = (tile0 + i) * 64 + r0i + lane;
            const int myt = (lane < 16 && slot < M) ? spair[2 * slot + 1] : -1;
            int curT = -1;
            unsigned m0 = 0, m1 = 0;
            for (int r = 0; r < 16; r++) {
                const int tg = __shfl(myt, r);
                const unsigned k2 = *(const unsigned*)&At[u][swz(r0i + r, cb)];
                const unsigned k0 = k2 & 0xFFFFu, k1 = k2 >> 16;
                if (tg != curT) {
                    if (curT >= 0) {
                        unsigned* p = &agg[(size_t)curT * 256 + cb];
                        atomicMax(p, m0); atomicMax(p + 1, m1);
                    }
                    curT = tg; m0 = k0; m1 = k1;
                } else {
                    m0 = m0 > k0 ? m0 : k0;
                    m1 = m1 > k1 ? m1 : k1;
                }
            }
            if (curT >= 0) {
                unsigned* p = &agg[(size_t)curT * 256 + cb];
                atomicMax(p, m0); atomicMax(p + 1, m1);
            }
        }
        __syncthreads();   // protect At[u] (next iter's gather target) reads
    }
}

// Final layer: agg keys -> XOR unmask -> GEMM3(W3'=W3*s2, b3') -> BN3 -> out
__global__ __launch_bounds__(256) void out_kernel(
    const unsigned* __restrict__ agg, int N,
    const unsigned short* __restrict__ W3b,
    const float* __restrict__ consts,
    const unsigned* __restrict__ mask2,
    float* __restrict__ out)
{
    __shared__ unsigned short At[32 * 256];

    const int t = threadIdx.x;
    const int base = blockIdx.x * 32;

    {
        const int row = t >> 3, part = t & 7;
        const int node = base + row;
        const int c0 = part * 32;
        if (node < N) {
            const unsigned* ap = agg + (size_t)node * 256 + c0;
            #pragma unroll
            for (int w = 0; w < 4; w++) {
                uint4 a = *(const uint4*)(ap + w * 8);
                uint4 b = *(const uint4*)(ap + w * 8 + 4);
                const uint4 mk = *(const uint4*)&mask2[(c0 + w * 8) >> 1];
                uint4 p;
                p.x = (a.x | (a.y << 16)) ^ mk.x;
                p.y = (a.z | (a.w << 16)) ^ mk.y;
                p.z = (b.x | (b.y << 16)) ^ mk.z;
                p.w = (b.z | (b.w << 16)) ^ mk.w;
                *(uint4*)&At[swz(row, c0 + w * 8)] = p;
            }
        } else {
            const uint4 z = {0u, 0u, 0u, 0u};
            #pragma unroll
            for (int w = 0; w < 4; w++) *(uint4*)&At[swz(row, c0 + w * 8)] = z;
        }
    }
    __syncthreads();

    const int lane = t & 63;
    const int wv   = t >> 6;
    const int n16  = lane & 15;
    const int qd   = lane >> 4;
    const int wc   = wv * 64;

    const f32x4 vzero = {0.f, 0.f, 0.f, 0.f};
    f32x4 acc[2][4];
    #pragma unroll
    for (int i = 0; i < 2; i++)
        #pragma unroll
        for (int j = 0; j < 4; j++) acc[i][j] = vzero;

    #pragma unroll
    for (int ks = 0; ks < 8; ks++) {
        const int k0 = ks * 32 + qd * 8;
        bf16x8 a[2];
        #pragma unroll
        for (int ri = 0; ri < 2; ri++)
            a[ri] = *(const bf16x8*)&At[swz(ri * 16 + n16, k0)];
        #pragma unroll
        for (int ci = 0; ci < 4; ci++) {
            bf16x8 b = *(const bf16x8*)&W3b[(size_t)(wc + ci * 16 + n16) * 256 + k0];
            #pragma unroll
            for (int ri = 0; ri < 2; ri++)
                acc[ri][ci] = __builtin_amdgcn_mfma_f32_16x16x32_bf16(a[ri], b, acc[ri][ci], 0, 0, 0);
        }
    }

    {
        const float* B3 = consts + 1536;
        const float* S3 = consts + 1536 + 256;
        const float* T3 = consts + 1536 + 512;
        #pragma unroll
        for (int ci = 0; ci < 4; ci++) {
            const int col = wc + ci * 16 + n16;
            const float bb = B3[col], ss = S3[col], tt = T3[col];
            #pragma unroll
            for (int ri = 0; ri < 2; ri++) {
                #pragma unroll
                for (int r = 0; r < 4; r++) {
                    const int row = ri * 16 + qd * 4 + r;
                    const int node = base + row;
                    if (node < N) {
                        float v = fmaxf(acc[ri][ci][r] + bb, 0.f) * ss + tt;
                        out[(size_t)node * 256 + col] = v;
                    }
                }
            }
        }
    }
}

extern "C" void kernel_launch(void* const* d_in, const int* in_sizes, int n_in,
                              void* d_out, int out_size, void* d_ws, size_t ws_size,
                              hipStream_t stream)
{
    const float* x  = (const float*)d_in[0];
    const int* eidx = (const int*)d_in[1];
    const int N = in_sizes[0] / 128;
    const int E = in_sizes[1] / 2;
    const int M = E + N;
    const int nTiles = (M + 63) / 64;

    char* ws = (char*)d_ws;
    unsigned short* W1b = (unsigned short*)(ws);
    unsigned short* W2b = (unsigned short*)(ws + 131072);
    unsigned short* W3b = (unsigned short*)(ws + 262144);
    float* consts       = (float*)(ws + 393216);                 // 2304 f32
    unsigned* mask2     = (unsigned*)(ws + 402432);              // 128 u32
    size_t off = 402944;
    unsigned* agg       = (unsigned*)(ws + off);       off += (size_t)N * 256 * 4;
    unsigned* count     = (unsigned*)(ws + off);       off += (size_t)N * 4;
    unsigned* cursor    = (unsigned*)(ws + off);       off += (size_t)N * 4;
    int* spair          = (int*)(ws + off);            off += (size_t)M * 8;
    unsigned short* Pb  = (unsigned short*)(ws + off); off += (size_t)N * 256 * 2;
    unsigned short* Qb  = (unsigned short*)(ws + off);

    hipMemsetAsync(agg, 0, (size_t)N * 256 * 4, stream);
    hipMemsetAsync(count, 0, (size_t)N * 4, stream);

    int work = M;
    if (65536 > work) work = 65536;
    hipLaunchKernelGGL(prep_kernel, dim3((work + 255) / 256), dim3(256), 0, stream,
        eidx, E, M,
        (const float*)d_in[2], (const float*)d_in[8], (const float*)d_in[14],
        (const float*)d_in[3], (const float*)d_in[4], (const float*)d_in[5],
        (const float*)d_in[6], (const float*)d_in[7],
        (const float*)d_in[9], (const float*)d_in[10], (const float*)d_in[11],
        (const float*)d_in[12], (const float*)d_in[13],
        (const float*)d_in[15], (const float*)d_in[16], (const float*)d_in[17],
        (const float*)d_in[18], (const float*)d_in[19],
        W1b, W2b, W3b, consts, mask2, count);

    hipLaunchKernelGGL(matvec_kernel, dim3(128), dim3(256), 0, stream,
        (const float*)d_in[8], (const float*)d_in[14], consts);

    hipLaunchKernelGGL(pq_kernel, dim3((N + 63) / 64), dim3(512), 0, stream,
        x, N, W1b, consts, Pb, Qb);

    hipLaunchKernelGGL(scan_kernel, dim3(1), dim3(1024), 0, stream,
        count, cursor, N);
    hipLaunchKernelGGL(scatter_kernel, dim3((M + 255) / 256), dim3(256), 0, stream,
        eidx, E, M, cursor, spair);

    hipLaunchKernelGGL(msg_kernel, dim3((nTiles + TPB - 1) / TPB), dim3(512), 0, stream,
        Pb, Qb, spair, M, W2b, consts, mask2, agg);

    hipLaunchKernelGGL(out_kernel, dim3((N + 31) / 32), dim3(256), 0, stream,
        agg, N, W3b, consts, mask2, (float*)d_out);
}

// Round 10
// 471.553 us; speedup vs baseline: 1.4323x; 1.4323x over previous
//
#include <hip/hip_runtime.h>
#include <stdint.h>

#define BN_EPS 1e-5f

typedef __bf16 bf16x8 __attribute__((ext_vector_type(8)));
typedef __bf16 bf16x2 __attribute__((ext_vector_type(2)));
typedef float  f32x4  __attribute__((ext_vector_type(4)));
typedef float  f32x2  __attribute__((ext_vector_type(2)));

__device__ __forceinline__ unsigned short f2bf(float f) {
    unsigned u = __float_as_uint(f);
    unsigned r = (u + 0x7FFFu + ((u >> 16) & 1u)) >> 16;
    return (unsigned short)r;
}
// HW packed f32x2 -> bf16x2 (v_cvt_pk_bf16_f32), RNE
__device__ __forceinline__ unsigned pkb(float a, float b) {
    f32x2 f; f.x = a; f.y = b;
    bf16x2 h = __builtin_convertvector(f, bf16x2);
    return *(unsigned*)&h;
}
// packed relu(p + q) on bf16 pairs
__device__ __forceinline__ unsigned ar2(unsigned p, unsigned q) {
    f32x2 a, b;
    a.x = __uint_as_float(p << 16);
    a.y = __uint_as_float(p & 0xFFFF0000u);
    b.x = __uint_as_float(q << 16);
    b.y = __uint_as_float(q & 0xFFFF0000u);
    f32x2 s = a + b;
    return pkb(fmaxf(s.x, 0.f), fmaxf(s.y, 0.f));
}
// LDS swizzle, 256-col ushort tile: 16B blocks XOR'd by row&7
__device__ __forceinline__ int swz(int row, int k) {
    const int blk = k >> 3;
    const int sb = (blk & 24) | ((blk ^ row) & 7);
    return (row << 8) + (sb << 3) + (k & 7);
}
// LDS swizzle, 128-col ushort tile
__device__ __forceinline__ int swz128(int row, int k) {
    const int blk = k >> 3;
    const int sb = (blk & 8) | ((blk ^ row) & 7);
    return (row << 7) + (sb << 3) + (k & 7);
}

// prep: W folds, sign masks, BN consts (biases get matvec folds later), histogram
__global__ void prep_kernel(
    const int* __restrict__ eidx,
    int E, int M,
    const float* __restrict__ W1, const float* __restrict__ W2, const float* __restrict__ W3,
    const float* __restrict__ b1, const float* __restrict__ g1, const float* __restrict__ be1,
    const float* __restrict__ m1, const float* __restrict__ v1,
    const float* __restrict__ b2, const float* __restrict__ g2, const float* __restrict__ be2,
    const float* __restrict__ m2, const float* __restrict__ v2,
    const float* __restrict__ b3, const float* __restrict__ g3, const float* __restrict__ be3,
    const float* __restrict__ m3, const float* __restrict__ v3,
    unsigned short* __restrict__ W1b, unsigned short* __restrict__ W2b,
    unsigned short* __restrict__ W3b, float* __restrict__ consts,
    unsigned* __restrict__ mask2, unsigned* __restrict__ count)
{
    const int idx = blockIdx.x * 256 + threadIdx.x;
    if (idx < 65536) {
        const int row = idx >> 8, c = idx & 255;
        float w1v = (c < 128) ? (W1[row * 256 + c] - W1[row * 256 + c + 128])
                              : W1[row * 256 + c];
        W1b[idx] = f2bf(w1v);
        const float s1c = g1[c] * rsqrtf(v1[c] + BN_EPS);
        W2b[idx] = f2bf(W2[idx] * s1c);
        const float s2c = g2[c] * rsqrtf(v2[c] + BN_EPS);
        W3b[idx] = f2bf(W3[idx] * s2c);
    }
    if (idx < 128) {
        const float sa = g2[2 * idx]     * rsqrtf(v2[2 * idx]     + BN_EPS);
        const float sb = g2[2 * idx + 1] * rsqrtf(v2[2 * idx + 1] + BN_EPS);
        mask2[idx] = (sa < 0.f ? 0xFFFFu : 0u) | ((sb < 0.f ? 0xFFFFu : 0u) << 16);
    }
    if (idx < 768) {
        const int l = idx >> 8, c = idx & 255;
        const float* bp  = l == 0 ? b1  : (l == 1 ? b2  : b3);
        const float* gp  = l == 0 ? g1  : (l == 1 ? g2  : g3);
        const float* bep = l == 0 ? be1 : (l == 1 ? be2 : be3);
        const float* mp  = l == 0 ? m1  : (l == 1 ? m2  : m3);
        const float* vp  = l == 0 ? v1  : (l == 1 ? v2  : v3);
        const float s = gp[c] * rsqrtf(vp[c] + BN_EPS);
        consts[l * 768 + c]       = bp[c];
        consts[l * 768 + 256 + c] = s;
        consts[l * 768 + 512 + c] = bep[c] - mp[c] * s;
    }
    if (idx < M) {
        const int tgt = (idx < E) ? eidx[E + idx] : (idx - E);
        atomicAdd(&count[tgt], 1u);
    }
}

// block 0: exclusive-sum scan of count -> cursor.
// blocks 1..32: matvec folds b2'' += W2@t1, b3' += W3@t2 (wave per col).
__global__ __launch_bounds__(1024) void scan_matvec_kernel(
    const unsigned* __restrict__ count, unsigned* __restrict__ cursor, int N,
    const float* __restrict__ W2, const float* __restrict__ W3,
    float* __restrict__ consts)
{
    const int t = threadIdx.x;
    if (blockIdx.x > 0) {
        const int g = (blockIdx.x - 1) * 16 + (t >> 6);   // 0..511
        const int lane = t & 63;
        const int l = g >> 8, c = g & 255;
        const float* W = l ? W3 : W2;
        const float* tv = consts + (l ? (768 + 512) : 512);
        float4 w4 = *(const float4*)&W[c * 256 + lane * 4];
        float4 t4 = *(const float4*)&tv[lane * 4];
        float s = w4.x * t4.x + w4.y * t4.y + w4.z * t4.z + w4.w * t4.w;
        #pragma unroll
        for (int d = 1; d < 64; d <<= 1) s += __shfl_xor(s, d);
        if (lane == 0) consts[(l ? 1536 : 768) + c] += s;
        return;
    }
    __shared__ unsigned part[1024];
    const int per = (N + 1023) / 1024;
    const int b = t * per;
    unsigned s = 0;
    if (b + per <= N && (per & 3) == 0) {
        for (int i = 0; i < per; i += 4) {
            uint4 c4 = *(const uint4*)(count + b + i);
            s += c4.x + c4.y + c4.z + c4.w;
        }
    } else {
        for (int i = 0; i < per; i++) if (b + i < N) s += count[b + i];
    }
    part[t] = s;
    __syncthreads();
    for (int off = 1; off < 1024; off <<= 1) {
        unsigned v = (t >= off) ? part[t - off] : 0u;
        __syncthreads();
        part[t] += v;
        __syncthreads();
    }
    unsigned run = (t > 0) ? part[t - 1] : 0u;
    for (int i = 0; i < per; i++) {
        if (b + i < N) {
            unsigned c = count[b + i];
            cursor[b + i] = run;
            run += c;
        }
    }
}

// fused: blocks [0,nScat): scatter (src,tgt) pairs into sorted position;
//        blocks [nScat,..): pq GEMM (P'=X@(W1a-W1b)^T+b1, Q=X@W1b^T)
__global__ __launch_bounds__(512) void scatpq_kernel(
    const int* __restrict__ eidx, int E, int M, int nScat,
    unsigned* __restrict__ cursor, int* __restrict__ spair,
    const float* __restrict__ x, int N,
    const unsigned short* __restrict__ W1b,
    const float* __restrict__ consts,
    unsigned short* __restrict__ Pb, unsigned short* __restrict__ Qb)
{
    __shared__ unsigned short Xs[64 * 128];
    const int t = threadIdx.x;

    if ((int)blockIdx.x < nScat) {
        const int i = blockIdx.x * 512 + t;
        if (i < M) {
            int s, tg;
            if (i < E) { s = eidx[i]; tg = eidx[E + i]; }
            else       { s = tg = i - E; }
            const unsigned pos = atomicAdd(&cursor[tg], 1u);
            int2* p = (int2*)spair;
            p[pos] = make_int2(s, tg);
        }
        return;
    }

    const int base = (blockIdx.x - nScat) * 64;
    {
        const int row = t >> 3, part = t & 7;
        const int node = base + row;
        const int c0 = part * 16;
        if (node < N) {
            const float* s = x + (size_t)node * 128 + c0;
            float4 a0 = *(const float4*)(s);
            float4 a1 = *(const float4*)(s + 4);
            float4 a2 = *(const float4*)(s + 8);
            float4 a3 = *(const float4*)(s + 12);
            uint4 p0 = {pkb(a0.x, a0.y), pkb(a0.z, a0.w), pkb(a1.x, a1.y), pkb(a1.z, a1.w)};
            uint4 p1 = {pkb(a2.x, a2.y), pkb(a2.z, a2.w), pkb(a3.x, a3.y), pkb(a3.z, a3.w)};
            *(uint4*)&Xs[swz128(row, c0)]     = p0;
            *(uint4*)&Xs[swz128(row, c0 + 8)] = p1;
        } else {
            const uint4 z = {0u, 0u, 0u, 0u};
            *(uint4*)&Xs[swz128(row, c0)]     = z;
            *(uint4*)&Xs[swz128(row, c0 + 8)] = z;
        }
    }
    __syncthreads();

    const int lane = t & 63;
    const int wv   = t >> 6;
    const int n16  = lane & 15;
    const int qd   = lane >> 4;
    const int wc   = wv * 32;

    const f32x4 vzero = {0.f, 0.f, 0.f, 0.f};

    #pragma unroll
    for (int ph = 0; ph < 2; ph++) {
        f32x4 acc[2][4];
        #pragma unroll
        for (int i = 0; i < 2; i++)
            #pragma unroll
            for (int j = 0; j < 4; j++) acc[i][j] = vzero;

        #pragma unroll
        for (int ks = 0; ks < 4; ks++) {
            const int k0 = ks * 32 + qd * 8;
            bf16x8 a[2], b[4];
            #pragma unroll
            for (int ci = 0; ci < 2; ci++)
                a[ci] = *(const bf16x8*)&W1b[(size_t)(wc + ci * 16 + n16) * 256 + ph * 128 + k0];
            #pragma unroll
            for (int rj = 0; rj < 4; rj++)
                b[rj] = *(const bf16x8*)&Xs[swz128(rj * 16 + n16, k0)];
            #pragma unroll
            for (int ci = 0; ci < 2; ci++)
                #pragma unroll
                for (int rj = 0; rj < 4; rj++)
                    acc[ci][rj] = __builtin_amdgcn_mfma_f32_16x16x32_bf16(a[ci], b[rj], acc[ci][rj], 0, 0, 0);
        }

        unsigned short* dst = ph == 0 ? Pb : Qb;
        #pragma unroll
        for (int ci = 0; ci < 2; ci++) {
            const int col0 = wc + ci * 16 + qd * 4;
            float4 bb = {0.f, 0.f, 0.f, 0.f};
            if (ph == 0) bb = *(const float4*)&consts[col0];
            #pragma unroll
            for (int rj = 0; rj < 4; rj++) {
                const int node = base + rj * 16 + n16;
                if (node < N) {
                    uint2 p = {pkb(acc[ci][rj][0] + bb.x, acc[ci][rj][1] + bb.y),
                               pkb(acc[ci][rj][2] + bb.z, acc[ci][rj][3] + bb.w)};
                    *(uint2*)(dst + (size_t)node * 256 + col0) = p;
                }
            }
        }
    }
}

// Fused: u1 = relu(P'[tgt]+Q[src]) -> GEMM2 -> epi2(raw bf16 keys) -> LDS segmax
// R7 structure (best measured). XCD swizzle: each XCD gets a contiguous range
// of sorted tiles so its P[tgt] working set (~2.6 MB) fits the 4 MB private L2.
__global__ __launch_bounds__(512) void msg_kernel(
    const unsigned short* __restrict__ Pb,
    const unsigned short* __restrict__ Qb,
    const int* __restrict__ spair,   // [M] (src,tgt) pairs, sorted by tgt
    int M, int chunk,
    const unsigned short* __restrict__ W2b,
    const float* __restrict__ consts,
    const unsigned* __restrict__ mask2,
    unsigned* __restrict__ agg)
{
    __shared__ unsigned short At[64 * 256];   // 32 KiB
    __shared__ int tgt_l[64];

    const int tile = (blockIdx.x & 7) * chunk + (blockIdx.x >> 3);
    if (tile * 64 >= M) return;
    const int base = tile * 64;
    const int t = threadIdx.x;

    // ---- gather+L1: u1 = relu(P'[tgt] + Q[src]) straight into LDS ----
    {
        const int row = t >> 3, part = t & 7;
        const int slot = base + row;
        const int c0 = part * 32;
        if (slot < M) {
            const int2 pr = *(const int2*)(spair + 2 * slot);   // (src, tgt)
            if (part == 0) tgt_l[row] = pr.y;
            const unsigned short* Pp = Pb + (size_t)pr.y * 256 + c0;
            const unsigned short* Qp = Qb + (size_t)pr.x * 256 + c0;
            uint4 P4[4], Q4[4];
            #pragma unroll
            for (int w = 0; w < 4; w++) P4[w] = *(const uint4*)(Pp + w * 8);
            #pragma unroll
            for (int w = 0; w < 4; w++) Q4[w] = *(const uint4*)(Qp + w * 8);
            #pragma unroll
            for (int w = 0; w < 4; w++) {
                uint4 u;
                u.x = ar2(P4[w].x, Q4[w].x);
                u.y = ar2(P4[w].y, Q4[w].y);
                u.z = ar2(P4[w].z, Q4[w].z);
                u.w = ar2(P4[w].w, Q4[w].w);
                *(uint4*)&At[swz(row, c0 + w * 8)] = u;
            }
        } else {
            if (part == 0) tgt_l[row] = -1;
            const uint4 z = {0u, 0u, 0u, 0u};
            #pragma unroll
            for (int w = 0; w < 4; w++) *(uint4*)&At[swz(row, c0 + w * 8)] = z;
        }
    }
    __syncthreads();

    const int lane = t & 63;
    const int wv   = t >> 6;
    const int n16  = lane & 15;
    const int qd   = lane >> 4;
    const int wc   = wv * 32;

    const f32x4 vzero = {0.f, 0.f, 0.f, 0.f};
    f32x4 acc[2][4];
    #pragma unroll
    for (int i = 0; i < 2; i++)
        #pragma unroll
        for (int j = 0; j < 4; j++) acc[i][j] = vzero;

    // ---- GEMM2: A=W2'(BN1-scaled), B=u1 ----
    #pragma unroll
    for (int ks = 0; ks < 8; ks++) {
        const int k0 = ks * 32 + qd * 8;
        bf16x8 a[2], b[4];
        #pragma unroll
        for (int ci = 0; ci < 2; ci++)
            a[ci] = *(const bf16x8*)&W2b[(size_t)(wc + ci * 16 + n16) * 256 + k0];
        #pragma unroll
        for (int rj = 0; rj < 4; rj++)
            b[rj] = *(const bf16x8*)&At[swz(rj * 16 + n16, k0)];
        #pragma unroll
        for (int ci = 0; ci < 2; ci++)
            #pragma unroll
            for (int rj = 0; rj < 4; rj++)
                acc[ci][rj] = __builtin_amdgcn_mfma_f32_16x16x32_bf16(a[ci], b[rj], acc[ci][rj], 0, 0, 0);
    }
    __syncthreads();

    // ---- epi2: r = relu(z2 + b2'') -> raw bf16 bits ^ signmask ----
    {
        const float* B2 = consts + 768;
        #pragma unroll
        for (int ci = 0; ci < 2; ci++) {
            const int col0 = wc + ci * 16 + qd * 4;
            const float4 bb = *(const float4*)&B2[col0];
            const uint2 mk = *(const uint2*)&mask2[col0 >> 1];
            #pragma unroll
            for (int rj = 0; rj < 4; rj++) {
                const int row = rj * 16 + n16;
                float r0 = fmaxf(acc[ci][rj][0] + bb.x, 0.f);
                float r1 = fmaxf(acc[ci][rj][1] + bb.y, 0.f);
                float r2 = fmaxf(acc[ci][rj][2] + bb.z, 0.f);
                float r3 = fmaxf(acc[ci][rj][3] + bb.w, 0.f);
                uint2 p = {pkb(r0, r1) ^ mk.x, pkb(r2, r3) ^ mk.y};
                *(uint2*)&At[swz(row, col0)] = p;
            }
        }
    }
    __syncthreads();

    // ---- segmented max: wave = 16 rows x 128 cols, lane = 2 cols ----
    {
        const int r0 = (wv & 3) * 16;
        const int cb = (wv >> 2) * 128 + lane * 2;
        const int myt = (lane < 16) ? tgt_l[r0 + lane] : -1;
        int curT = -1;
        unsigned m0 = 0, m1 = 0;
        for (int r = 0; r < 16; r++) {
            const int tg = __shfl(myt, r);            // wave-uniform
            const unsigned k2 = *(const unsigned*)&At[swz(r0 + r, cb)];
            const unsigned k0 = k2 & 0xFFFFu, k1 = k2 >> 16;
            if (tg != curT) {
                if (curT >= 0) {
                    unsigned* p = &agg[(size_t)curT * 256 + cb];
                    atomicMax(p, m0); atomicMax(p + 1, m1);
                }
                curT = tg; m0 = k0; m1 = k1;
            } else {
                m0 = m0 > k0 ? m0 : k0;
                m1 = m1 > k1 ? m1 : k1;
            }
        }
        if (curT >= 0) {
            unsigned* p = &agg[(size_t)curT * 256 + cb];
            atomicMax(p, m0); atomicMax(p + 1, m1);
        }
    }
}

// Final layer: agg keys -> XOR unmask -> GEMM3(W3'=W3*s2, b3') -> BN3 -> out
__global__ __launch_bounds__(256) void out_kernel(
    const unsigned* __restrict__ agg, int N,
    const unsigned short* __restrict__ W3b,
    const float* __restrict__ consts,
    const unsigned* __restrict__ mask2,
    float* __restrict__ out)
{
    __shared__ unsigned short At[32 * 256];

    const int t = threadIdx.x;
    const int base = blockIdx.x * 32;

    {
        const int row = t >> 3, part = t & 7;
        const int node = base + row;
        const int c0 = part * 32;
        if (node < N) {
            const unsigned* ap = agg + (size_t)node * 256 + c0;
            #pragma unroll
            for (int w = 0; w < 4; w++) {
                uint4 a = *(const uint4*)(ap + w * 8);
                uint4 b = *(const uint4*)(ap + w * 8 + 4);
                const uint4 mk = *(const uint4*)&mask2[(c0 + w * 8) >> 1];
                uint4 p;
                p.x = (a.x | (a.y << 16)) ^ mk.x;
                p.y = (a.z | (a.w << 16)) ^ mk.y;
                p.z = (b.x | (b.y << 16)) ^ mk.z;
                p.w = (b.z | (b.w << 16)) ^ mk.w;
                *(uint4*)&At[swz(row, c0 + w * 8)] = p;
            }
        } else {
            const uint4 z = {0u, 0u, 0u, 0u};
            #pragma unroll
            for (int w = 0; w < 4; w++) *(uint4*)&At[swz(row, c0 + w * 8)] = z;
        }
    }
    __syncthreads();

    const int lane = t & 63;
    const int wv   = t >> 6;
    const int n16  = lane & 15;
    const int qd   = lane >> 4;
    const int wc   = wv * 64;

    const f32x4 vzero = {0.f, 0.f, 0.f, 0.f};
    f32x4 acc[2][4];
    #pragma unroll
    for (int i = 0; i < 2; i++)
        #pragma unroll
        for (int j = 0; j < 4; j++) acc[i][j] = vzero;

    #pragma unroll
    for (int ks = 0; ks < 8; ks++) {
        const int k0 = ks * 32 + qd * 8;
        bf16x8 a[2];
        #pragma unroll
        for (int ri = 0; ri < 2; ri++)
            a[ri] = *(const bf16x8*)&At[swz(ri * 16 + n16, k0)];
        #pragma unroll
        for (int ci = 0; ci < 4; ci++) {
            bf16x8 b = *(const bf16x8*)&W3b[(size_t)(wc + ci * 16 + n16) * 256 + k0];
            #pragma unroll
            for (int ri = 0; ri < 2; ri++)
                acc[ri][ci] = __builtin_amdgcn_mfma_f32_16x16x32_bf16(a[ri], b, acc[ri][ci], 0, 0, 0);
        }
    }

    {
        const float* B3 = consts + 1536;
        const float* S3 = consts + 1536 + 256;
        const float* T3 = consts + 1536 + 512;
        #pragma unroll
        for (int ci = 0; ci < 4; ci++) {
            const int col = wc + ci * 16 + n16;
            const float bb = B3[col], ss = S3[col], tt = T3[col];
            #pragma unroll
            for (int ri = 0; ri < 2; ri++) {
                #pragma unroll
                for (int r = 0; r < 4; r++) {
                    const int row = ri * 16 + qd * 4 + r;
                    const int node = base + row;
                    if (node < N) {
                        float v = fmaxf(acc[ri][ci][r] + bb, 0.f) * ss + tt;
                        out[(size_t)node * 256 + col] = v;
                    }
                }
            }
        }
    }
}

extern "C" void kernel_launch(void* const* d_in, const int* in_sizes, int n_in,
                              void* d_out, int out_size, void* d_ws, size_t ws_size,
                              hipStream_t stream)
{
    const float* x  = (const float*)d_in[0];
    const int* eidx = (const int*)d_in[1];
    const int N = in_sizes[0] / 128;
    const int E = in_sizes[1] / 2;
    const int M = E + N;
    const int nTiles = (M + 63) / 64;
    const int chunk = (nTiles + 7) / 8;      // tiles per XCD
    const int nScat = (M + 511) / 512;
    const int nPQ = (N + 63) / 64;

    char* ws = (char*)d_ws;
    unsigned short* W1b = (unsigned short*)(ws);
    unsigned short* W2b = (unsigned short*)(ws + 131072);
    unsigned short* W3b = (unsigned short*)(ws + 262144);
    float* consts       = (float*)(ws + 393216);                 // 2304 f32
    unsigned* mask2     = (unsigned*)(ws + 402432);              // 128 u32
    size_t off = 402944;
    unsigned* agg       = (unsigned*)(ws + off);       off += (size_t)N * 256 * 4;
    unsigned* count     = (unsigned*)(ws + off);       off += (size_t)N * 4;
    unsigned* cursor    = (unsigned*)(ws + off);       off += (size_t)N * 4;
    int* spair          = (int*)(ws + off);            off += (size_t)M * 8;
    unsigned short* Pb  = (unsigned short*)(ws + off); off += (size_t)N * 256 * 2;
    unsigned short* Qb  = (unsigned short*)(ws + off);

    hipMemsetAsync(agg, 0, (size_t)N * 256 * 4, stream);
    hipMemsetAsync(count, 0, (size_t)N * 4, stream);

    int work = M;
    if (65536 > work) work = 65536;
    hipLaunchKernelGGL(prep_kernel, dim3((work + 255) / 256), dim3(256), 0, stream,
        eidx, E, M,
        (const float*)d_in[2], (const float*)d_in[8], (const float*)d_in[14],
        (const float*)d_in[3], (const float*)d_in[4], (const float*)d_in[5],
        (const float*)d_in[6], (const float*)d_in[7],
        (const float*)d_in[9], (const float*)d_in[10], (const float*)d_in[11],
        (const float*)d_in[12], (const float*)d_in[13],
        (const float*)d_in[15], (const float*)d_in[16], (const float*)d_in[17],
        (const float*)d_in[18], (const float*)d_in[19],
        W1b, W2b, W3b, consts, mask2, count);

    hipLaunchKernelGGL(scan_matvec_kernel, dim3(33), dim3(1024), 0, stream,
        count, cursor, N,
        (const float*)d_in[8], (const float*)d_in[14], consts);

    hipLaunchKernelGGL(scatpq_kernel, dim3(nScat + nPQ), dim3(512), 0, stream,
        eidx, E, M, nScat, cursor, spair,
        x, N, W1b, consts, Pb, Qb);

    hipLaunchKernelGGL(msg_kernel, dim3(chunk * 8), dim3(512), 0, stream,
        Pb, Qb, spair, M, chunk, W2b, consts, mask2, agg);

    hipLaunchKernelGGL(out_kernel, dim3((N + 31) / 32), dim3(256), 0, stream,
        agg, N, W3b, consts, mask2, (float*)d_out);
}